// Round 1
// baseline (1172.669 us; speedup 1.0000x reference)
//
#include <hip/hip_runtime.h>
#include <math.h>

// Problem constants
#define CC 62
#define TT 2000
#define BB 256
#define VECN 1953          // C*(C+1)/2
#define HID 64
#define NCLS 3
#define NPART 4            // t-parts for Grammian partials
#define TCHUNK 500         // TT / NPART
#define TTILE 50           // t-tile
#define NTILES 10          // TCHUNK / TTILE
#define LDT 66             // sXT row stride (doubles)
#define NG 31              // disjoint pairs per round
#define GLD 64             // sGd column stride in doubles (512B, swizzled layout)

__device__ __forceinline__ void decodePi(int pi, int& i, int& j)
{
    int ii = 0, rem = pi;
    while (rem >= CC - ii) { rem -= (CC - ii); ++ii; }
    i = ii; j = ii + rem;
}

// round-robin (circle method) pair schedule: 31 disjoint pairs, 61 rounds
__device__ __forceinline__ void pairPQ(int r, int k, int& p, int& q)
{
    if (k == 0) { p = 0; q = 1 + (r + 60) % 61; }
    else {
        p = 1 + (r + k - 1) % 61;
        q = 1 + (r + 60 - k) % 61;
    }
    if (p > q) { int t = p; p = q; q = t; }
}

// Swizzled row position inside a 512B column: rows grouped in 8-row blocks
// (one block per Jacobi lane l = i>>3); within a block the four 16B chunks
// are XOR-permuted by ((l>>1)&3) so that a group's 4 ds_read_b128 hit all
// 8 16B slots of every 128B bank window exactly once -> conflict-minimal.
__device__ __forceinline__ int swzRow(int i)
{
    int l = i >> 3;
    int c = (i >> 1) & 3;
    int cs = c ^ ((l >> 1) & 3);
    return (l << 3) | (cs << 1) | (i & 1);
}

// ---------------------------------------------------------------------------
// K1: raw-x fp64 partial Grammian S = sum_t x x^T (upper-tri packed) and
//     partial sums m = sum_t x over a 500-sample t-chunk. NO conv here:
//     cov(Wx+b) = W cov(x) W^T is applied in k2's prologue.
// grid = (B, NPART), block = 192.  (unchanged this round)
// ---------------------------------------------------------------------------
__global__ __launch_bounds__(192) void k1_gram(
    const float* __restrict__ x, double* __restrict__ S,
    double* __restrict__ M)
{
    const int b = blockIdx.x, part = blockIdx.y, tid = threadIdx.x;

    __shared__ double sXT[TTILE * LDT];   // [t][c], 16B-aligned rows
    __shared__ double sMP[192];

    // loader mapping: 3 threads per channel row
    const int lc = tid / 3, lsub = tid - lc * 3;
    const int lt0 = (lsub == 0) ? 0 : (lsub == 1 ? 17 : 34);
    const int lt1 = (lsub == 0) ? 17 : (lsub == 1 ? 34 : 50);
    const bool loader = (lc < CC);

    // Grammian mapping: thread u<136 -> group-pair (gi<=gj) of 16 groups of 4
    int gi = 0, gj = 0;
    if (tid < 136) {
        int g = 0, rem = tid;
        while (rem >= 16 - g) { rem -= (16 - g); ++g; }
        gi = g; gj = g + rem;
    }
    const bool gram = (tid < 136);
    const int c0 = 4 * gi, c1 = 4 * gj;

    double acc[4][4];
#pragma unroll
    for (int a = 0; a < 4; ++a)
#pragma unroll
        for (int c = 0; c < 4; ++c) acc[a][c] = 0.0;
    double macc = 0.0;

    // zero pad channels 62..65
    if (tid < TTILE) {
        sXT[tid * LDT + 62] = 0.0; sXT[tid * LDT + 63] = 0.0;
        sXT[tid * LDT + 64] = 0.0; sXT[tid * LDT + 65] = 0.0;
    }

    const float* xb = x + (size_t)b * CC * TT;
    const int tbase = part * TCHUNK;

    for (int tile = 0; tile < NTILES; ++tile) {
        const int t0 = tbase + tile * TTILE;
        __syncthreads();   // previous tile consumed (also covers pad init)
        if (loader) {
            const float* xr = xb + (size_t)lc * TT + t0;
            for (int t = lt0; t < lt1; ++t) {
                float v = xr[t];
                macc += (double)v;
                sXT[t * LDT + lc] = (double)v;
            }
        }
        __syncthreads();
        if (gram) {
            for (int t = 0; t < TTILE; ++t) {
                const double* rowt = &sXT[t * LDT];
                double2 A0 = *reinterpret_cast<const double2*>(&rowt[c0]);
                double2 A1 = *reinterpret_cast<const double2*>(&rowt[c0 + 2]);
                double2 B0 = *reinterpret_cast<const double2*>(&rowt[c1]);
                double2 B1 = *reinterpret_cast<const double2*>(&rowt[c1 + 2]);
                acc[0][0] += A0.x * B0.x; acc[0][1] += A0.x * B0.y;
                acc[0][2] += A0.x * B1.x; acc[0][3] += A0.x * B1.y;
                acc[1][0] += A0.y * B0.x; acc[1][1] += A0.y * B0.y;
                acc[1][2] += A0.y * B1.x; acc[1][3] += A0.y * B1.y;
                acc[2][0] += A1.x * B0.x; acc[2][1] += A1.x * B0.y;
                acc[2][2] += A1.x * B1.x; acc[2][3] += A1.x * B1.y;
                acc[3][0] += A1.y * B0.x; acc[3][1] += A1.y * B0.y;
                acc[3][2] += A1.y * B1.x; acc[3][3] += A1.y * B1.y;
            }
        }
    }
    __syncthreads();
    sMP[tid] = macc;
    __syncthreads();
    if (tid < CC)
        M[((size_t)b * NPART + part) * 64 + tid] =
            sMP[tid * 3] + sMP[tid * 3 + 1] + sMP[tid * 3 + 2];

    if (gram) {
        double* Sb = S + ((size_t)b * NPART + part) * VECN;
#pragma unroll
        for (int a = 0; a < 4; ++a) {
            int i = c0 + a;
#pragma unroll
            for (int c = 0; c < 4; ++c) {
                int j = c1 + c;
                if (j < CC && i <= j) {
                    int pi = i * CC - (i * (i - 1)) / 2 + (j - i);
                    Sb[pi] = acc[a][c];
                }
            }
        }
    }
}

// ---------------------------------------------------------------------------
// K2: assemble cov_x (packed), A = W cov_x W^T + eps I, ONE-SIDED Jacobi on
//     G = A, then log_cov = G diag(log(lam)/lam^2) G^T -> fp32 triu vec.
//
// RESTRUCTURED THIS ROUND (latency-bound: 1 block/CU, serial barrier rounds):
//  - 256 threads (4 waves, one per SIMD), 8 lanes per pair (31 groups).
//    Shuffle-reduce 4->3 steps, barrier 8->4 waves, 2x per-lane ILP.
//  - sGd columns are 512B (GLD=64) with chunk-XOR swizzle: the rotation
//    loop's ds_read/write_b128 are bank-conflict-minimal (8-phase floor).
//  - Algorithm/thresholds/fp32 rotation params unchanged.
// grid = B, block = 256. 1 barrier/round. Lane lt owns rows 8lt..8lt+7.
// ---------------------------------------------------------------------------
__global__ __launch_bounds__(256) void k2_eig(
    const double* __restrict__ S, const double* __restrict__ M,
    const float* __restrict__ cw, float* __restrict__ vecout)
{
    const int b = blockIdx.x, tid = threadIdx.x;

    __shared__ __align__(16) double sGd[CC * GLD]; // column-major, swizzled rows
    __shared__ double sC[VECN];        // packed upper-tri cov_x
    __shared__ double sU[4 * 64];
    __shared__ double sNorm[64];
    __shared__ double sD[64];
    __shared__ double sMean[64];
    __shared__ int    sPair[61 * NG];
    __shared__ int    sFlag;

    for (int e = tid; e < 61 * NG; e += 256) {
        int r = e / NG, k = e - r * NG;
        int p, q; pairPQ(r, k, p, q);
        sPair[e] = p | (q << 8);
    }
    if (tid < CC) {
        double mm = 0.0;
        for (int p = 0; p < NPART; ++p) mm += M[((size_t)b * NPART + p) * 64 + tid];
        sMean[tid] = mm / (double)TT;
    }
    for (int e = tid; e < CC * GLD; e += 256) sGd[e] = 0.0;
    __syncthreads();

    // packed cov_x = (S - T m m^T)/(T-1)
    for (int pi = tid; pi < VECN; pi += 256) {
        int i, j; decodePi(pi, i, j);
        double s = 0.0;
        for (int p = 0; p < NPART; ++p) s += S[((size_t)b * NPART + p) * VECN + pi];
        sC[pi] = (s - (double)TT * sMean[i] * sMean[j]) / 1999.0;
    }
    __syncthreads();

    // A = W C W^T + eps I, chunks of 4 output columns (256 threads)
    const int jj = tid >> 6, kk = tid & 63;
    for (int j0 = 0; j0 < CC; j0 += 4) {
        const int j = j0 + jj;
        if (kk < CC && j < CC) {
            const float* wr = cw + j * CC;
            double a = 0.0; int idx = kk;
            for (int l = 0; l < kk; ++l) { a += sC[idx] * (double)wr[l]; idx += 61 - l; }
            for (int l = kk; l < CC; ++l) { a += sC[idx] * (double)wr[l]; idx += 1; }
            sU[jj * 64 + kk] = a;    // u_j[k] = (C w_j)[k]
        }
        __syncthreads();
        const int i = kk;
        if (i < CC && j < CC && i <= j) {
            const float* wi = cw + i * CC;
            double a = (i == j) ? 1e-3 : 0.0;
            for (int l = 0; l < CC; ++l) a += (double)wi[l] * sU[jj * 64 + l];
            sGd[j * GLD + swzRow(i)] = a;
            sGd[i * GLD + swzRow(j)] = a;
        }
        __syncthreads();
    }

    // initial column norms n_k = ||g_k||^2 (swizzle is a permutation: sum as-is)
    if (tid < CC) {
        const double* col = &sGd[tid * GLD];
        double n = 0.0;
        for (int i2 = 0; i2 < 64; ++i2) n += col[i2] * col[i2];
        sNorm[tid] = n;
    }
    __syncthreads();

    // one-sided Jacobi: group g (8 lanes) handles pair g each round;
    // lane lt owns rows 8lt..8lt+7 (4 x double2, chunk-XOR swizzled)
    const int g = tid >> 3, lt = tid & 7;
    const bool act = (g < NG);
    const int sel = (lt >> 1) & 3;
    const int m0 = sel, m1 = 1 ^ sel, m2 = 2 ^ sel, m3 = 3 ^ sel;
    double2* gbase = reinterpret_cast<double2*>(sGd);
    const int lbase = lt << 2;           // lane block offset in double2 units

    for (int sweep = 0; sweep < 20; ++sweep) {
        if (tid == 0) sFlag = 0;
        __syncthreads();
        for (int r = 0; r < 61; ++r) {
            if (act) {
                int pq = sPair[r * NG + g];
                int p = pq & 255, q = pq >> 8;
                double2* cp = gbase + (p << 5) + lbase;   // column p, this lane
                double2* cq = gbase + (q << 5) + lbase;
                double2 P0 = cp[m0], P1 = cp[m1], P2 = cp[m2], P3 = cp[m3];
                double2 Q0 = cq[m0], Q1 = cq[m1], Q2 = cq[m2], Q3 = cq[m3];
                double d = P0.x * Q0.x + P0.y * Q0.y + P1.x * Q1.x + P1.y * Q1.y
                         + P2.x * Q2.x + P2.y * Q2.y + P3.x * Q3.x + P3.y * Q3.y;
                d += __shfl_xor(d, 4, 8);
                d += __shfl_xor(d, 2, 8);
                d += __shfl_xor(d, 1, 8);
                double np = sNorm[p], nq = sNorm[q];
                if (d * d > np * nq * 1e-12) {
                    // fp32 rotation params (residual ~1e-7*|d| < threshold)
                    float thf = (float)(nq - np) / (2.0f * (float)d);
                    float af = fabsf(thf);
                    float tf = 1.0f / (af + sqrtf(af * af + 1.0f));
                    if (thf < 0.0f) tf = -tf;
                    float cf = rsqrtf(tf * tf + 1.0f);
                    double c = (double)cf, sn = (double)(tf * cf);
                    cp[m0] = make_double2(c * P0.x - sn * Q0.x, c * P0.y - sn * Q0.y);
                    cp[m1] = make_double2(c * P1.x - sn * Q1.x, c * P1.y - sn * Q1.y);
                    cp[m2] = make_double2(c * P2.x - sn * Q2.x, c * P2.y - sn * Q2.y);
                    cp[m3] = make_double2(c * P3.x - sn * Q3.x, c * P3.y - sn * Q3.y);
                    cq[m0] = make_double2(sn * P0.x + c * Q0.x, sn * P0.y + c * Q0.y);
                    cq[m1] = make_double2(sn * P1.x + c * Q1.x, sn * P1.y + c * Q1.y);
                    cq[m2] = make_double2(sn * P2.x + c * Q2.x, sn * P2.y + c * Q2.y);
                    cq[m3] = make_double2(sn * P3.x + c * Q3.x, sn * P3.y + c * Q3.y);
                    if (lt == 0) {
                        double td = (double)tf * d;
                        sNorm[p] = np - td; sNorm[q] = nq + td;
                        sFlag = 1;
                    }
                }
            }
            __syncthreads();
        }
        int flag = sFlag;
        __syncthreads();
        if (!flag) break;
    }

    // lam_k^2 = ||g_k||^2 ; d_k = log(max(lam,1e-6))/lam^2
    if (tid < CC) {
        const double* col = &sGd[tid * GLD];
        double n = 0.0;
        for (int i5 = 0; i5 < 64; ++i5) n += col[i5] * col[i5];
        double lamv = sqrt(n);
        sD[tid] = log(fmax(lamv, 1e-6)) / n;
    }
    __syncthreads();

    float* vb = vecout + (size_t)b * VECN;
    for (int pi = tid; pi < VECN; pi += 256) {
        int i, j; decodePi(pi, i, j);
        const int si = swzRow(i), sj = swzRow(j);
        double a = 0.0;
        for (int k2 = 0; k2 < CC; ++k2)
            a += sD[k2] * sGd[k2 * GLD + si] * sGd[k2 * GLD + sj];
        vb[pi] = (float)a;
    }
}

// ---------------------------------------------------------------------------
// K3: feat = relu(vec @ proj_w^T + proj_b); logits = feat @ head_w^T + head_b
// grid = B, block = 256 (4-way K-split per hidden unit for latency hiding)
// ---------------------------------------------------------------------------
__global__ __launch_bounds__(256) void k3_mlp(
    const float* __restrict__ vecin, const float* __restrict__ pw,
    const float* __restrict__ pb, const float* __restrict__ hw,
    const float* __restrict__ hb, float* __restrict__ out)
{
    const int b = blockIdx.x;
    const int tid = threadIdx.x;
    __shared__ float sv[VECN];
    __shared__ float sp[4][HID];
    __shared__ float sf[HID];
    for (int k = tid; k < VECN; k += 256) sv[k] = vecin[(size_t)b * VECN + k];
    __syncthreads();
    const int h = tid & 63, pp = tid >> 6;
    const int k0 = (pp * VECN) >> 2, k1 = ((pp + 1) * VECN) >> 2;
    float acc = 0.0f;
    const float* w = pw + (size_t)h * VECN;
    for (int k = k0; k < k1; ++k) acc += sv[k] * w[k];
    sp[pp][h] = acc;
    __syncthreads();
    if (tid < HID) {
        float a = sp[0][tid] + sp[1][tid] + sp[2][tid] + sp[3][tid] + pb[tid];
        sf[tid] = fmaxf(a, 0.0f);
    }
    __syncthreads();
    if (tid < NCLS) {
        float o = hb[tid];
        for (int hh = 0; hh < HID; ++hh) o += sf[hh] * hw[tid * HID + hh];
        out[b * NCLS + tid] = o;
    }
}

// ---------------------------------------------------------------------------
extern "C" void kernel_launch(void* const* d_in, const int* in_sizes, int n_in,
                              void* d_out, int out_size, void* d_ws, size_t ws_size,
                              hipStream_t stream)
{
    const float* x  = (const float*)d_in[0];
    const float* cw = (const float*)d_in[1];
    // d_in[2] = conv bias: cancels in covariance, unused
    const float* pw = (const float*)d_in[3];
    const float* pb = (const float*)d_in[4];
    const float* hw = (const float*)d_in[5];
    const float* hb = (const float*)d_in[6];
    float* out = (float*)d_out;

    // workspace: S [B*NPART][VECN] fp64 (16MB), M [B*NPART][64] fp64 (0.5MB),
    //            vec [B][VECN] fp32 (2MB)
    double* S = (double*)d_ws;
    double* M = S + (size_t)BB * NPART * VECN;
    float* vec = (float*)(M + (size_t)BB * NPART * 64);

    dim3 g1(BB, NPART);
    k1_gram<<<g1, 192, 0, stream>>>(x, S, M);
    k2_eig<<<BB, 256, 0, stream>>>(S, M, cw, vec);
    k3_mlp<<<BB, 256, 0, stream>>>(vec, pw, pb, hw, hb, out);
}

// Round 2
// 1086.318 us; speedup vs baseline: 1.0795x; 1.0795x over previous
//
#include <hip/hip_runtime.h>
#include <math.h>

// Problem constants
#define CC 62
#define TT 2000
#define BB 256
#define VECN 1953          // C*(C+1)/2
#define HID 64
#define NCLS 3
#define TTILE 50           // t-tile
#define NTILES 40          // TT / TTILE
#define LDT 66             // sXT row stride (doubles)
#define LDG 66             // k2 G column stride (doubles)
#define NG 31              // disjoint pairs per round
#define SLD 64             // S row stride (full 64x64 fp64 block per batch)

__device__ __forceinline__ void decodePi(int pi, int& i, int& j)
{
    int ii = 0, rem = pi;
    while (rem >= CC - ii) { rem -= (CC - ii); ++ii; }
    i = ii; j = ii + rem;
}

// round-robin (circle method) pair schedule: 31 disjoint pairs, 61 rounds
__device__ __forceinline__ void pairPQ(int r, int k, int& p, int& q)
{
    if (k == 0) { p = 0; q = 1 + (r + 60) % 61; }
    else {
        p = 1 + (r + k - 1) % 61;
        q = 1 + (r + 60 - k) % 61;
    }
    if (p > q) { int t = p; p = q; q = t; }
}

// ---------------------------------------------------------------------------
// K1 (REWRITTEN): raw-x fp64 Grammian S = sum_t x~ x~^T over the FULL T range,
// one block per batch. x~ is x padded with a ones-row at channel 62, so
// S[i][62] = sum_t x_i  (the mean numerator) falls out of the same GEMM.
//  - 320 threads (5 waves): 136 chunk-pairs x 2-way k-split = 272 gram lanes
//    (~1.06 gram waves/SIMD -> fp64-FMA issue-bound ~27us floor)
//  - T14 reg-staged prefetch: every thread loads 5 float2 (coalesced) for
//    tile t+1 while tile t computes; HBM latency hides under 16-FMA t-loop.
// grid = B, block = 320. S layout: full 64x64 fp64 per batch (upper written).
// ---------------------------------------------------------------------------
__global__ __launch_bounds__(320) void k1_gram(
    const float* __restrict__ x, double* __restrict__ S)
{
    const int b = blockIdx.x, tid = threadIdx.x;

    __shared__ double sXT[TTILE * LDT];   // [t][chan], 26.4KB

    // gram mapping: pair2 = chunk-pair (gi<=gj) of 16 groups of 4 channels,
    // ks = t-parity split
    const int pair2 = tid >> 1, ks = tid & 1;
    const bool gram = (pair2 < 136);
    int gi = 0, gj = 0;
    if (gram) {
        int g = 0, rem = pair2;
        while (rem >= 16 - g) { rem -= (16 - g); ++g; }
        gi = g; gj = g + rem;
    }
    const int c0 = 4 * gi, c1 = 4 * gj;

    double acc[4][4];
#pragma unroll
    for (int a = 0; a < 4; ++a)
#pragma unroll
        for (int c = 0; c < 4; ++c) acc[a][c] = 0.0;

    // pad channels: row 62 = ones (mean trick), row 63 = zero
    if (tid < TTILE) {
        sXT[tid * LDT + 62] = 1.0;
        sXT[tid * LDT + 63] = 0.0;
    }

    const float* xb = x + (size_t)b * (CC * TT);

    // each tile = 62 rows x 50 t = 1550 float2 loads spread over 320 threads
    float2 pre[5];

    // prologue: prefetch tile 0
    {
#pragma unroll
        for (int s = 0; s < 5; ++s) {
            int e = tid + 320 * s;
            if (e < 1550) {
                int c = e / 25, kq = e - 25 * c;
                pre[s] = *reinterpret_cast<const float2*>(
                    xb + (size_t)c * TT + 2 * kq);
            }
        }
    }

    for (int tile = 0; tile < NTILES; ++tile) {
        __syncthreads();   // previous tile fully consumed
        // stage regs -> LDS
#pragma unroll
        for (int s = 0; s < 5; ++s) {
            int e = tid + 320 * s;
            if (e < 1550) {
                int c = e / 25, kq = e - 25 * c;
                sXT[(2 * kq) * LDT + c]     = (double)pre[s].x;
                sXT[(2 * kq + 1) * LDT + c] = (double)pre[s].y;
            }
        }
        // issue prefetch for next tile (in flight during compute)
        if (tile + 1 < NTILES) {
            const float* xt = xb + (tile + 1) * TTILE;
#pragma unroll
            for (int s = 0; s < 5; ++s) {
                int e = tid + 320 * s;
                if (e < 1550) {
                    int c = e / 25, kq = e - 25 * c;
                    pre[s] = *reinterpret_cast<const float2*>(
                        xt + (size_t)c * TT + 2 * kq);
                }
            }
        }
        __syncthreads();   // staged tile visible
        if (gram) {
            for (int t = ks; t < TTILE; t += 2) {
                const double* rowt = &sXT[t * LDT];
                double2 A0 = *reinterpret_cast<const double2*>(&rowt[c0]);
                double2 A1 = *reinterpret_cast<const double2*>(&rowt[c0 + 2]);
                double2 B0 = *reinterpret_cast<const double2*>(&rowt[c1]);
                double2 B1 = *reinterpret_cast<const double2*>(&rowt[c1 + 2]);
                acc[0][0] += A0.x * B0.x; acc[0][1] += A0.x * B0.y;
                acc[0][2] += A0.x * B1.x; acc[0][3] += A0.x * B1.y;
                acc[1][0] += A0.y * B0.x; acc[1][1] += A0.y * B0.y;
                acc[1][2] += A0.y * B1.x; acc[1][3] += A0.y * B1.y;
                acc[2][0] += A1.x * B0.x; acc[2][1] += A1.x * B0.y;
                acc[2][2] += A1.x * B1.x; acc[2][3] += A1.x * B1.y;
                acc[3][0] += A1.y * B0.x; acc[3][1] += A1.y * B0.y;
                acc[3][2] += A1.y * B1.x; acc[3][3] += A1.y * B1.y;
            }
        }
    }

    // k-split reduction through LDS (reuse sXT), then global write
    __syncthreads();
    double* sRed = sXT;   // 136*16 doubles = 17.4KB <= 26.4KB
    if (gram && ks == 1) {
#pragma unroll
        for (int a = 0; a < 4; ++a)
#pragma unroll
            for (int c = 0; c < 4; ++c)
                sRed[pair2 * 16 + a * 4 + c] = acc[a][c];
    }
    __syncthreads();
    if (gram && ks == 0) {
        double* Sb = S + (size_t)b * (SLD * 64);
#pragma unroll
        for (int a = 0; a < 4; ++a) {
            int i = c0 + a;
#pragma unroll
            for (int c = 0; c < 4; ++c) {
                int j = c1 + c;
                if (i <= j && j <= 62)
                    Sb[i * SLD + j] = acc[a][c] + sRed[pair2 * 16 + a * 4 + c];
            }
        }
    }
}

// ---------------------------------------------------------------------------
// K2 (REVERTED to round-0 structure: 512 thr, 16-lane groups, LDG=66 —
// measured 660us): assemble cov_x (packed), A = W cov_x W^T + eps I,
// one-sided Jacobi (fp32 rotation params, fp64 apply, cached norms), then
// log_cov = G diag(log(lam)/lam^2) G^T -> fp32 triu vec.
// Only interface change: S is a full 64x64 fp64 block; mean = S[i][62]/T.
// grid = B, block = 512. 1 barrier/round. Lane lt owns rows 4lt..4lt+3.
// ---------------------------------------------------------------------------
__global__ __launch_bounds__(512) void k2_eig(
    const double* __restrict__ S, const float* __restrict__ cw,
    float* __restrict__ vecout)
{
    const int b = blockIdx.x, tid = threadIdx.x;

    __shared__ double sG[CC * LDG];    // column-major, rows padded to 64+ w/ 0
    __shared__ double sC[VECN];        // packed upper-tri cov_x
    __shared__ double sU[8 * 64];
    __shared__ double sNorm[64];
    __shared__ double sD[64];
    __shared__ double sMean[64];
    __shared__ int    sPair[61 * NG];
    __shared__ int    sFlag;

    const double* Sb = S + (size_t)b * (SLD * 64);

    for (int e = tid; e < 61 * NG; e += 512) {
        int r = e / NG, k = e - r * NG;
        int p, q; pairPQ(r, k, p, q);
        sPair[e] = p | (q << 8);
    }
    if (tid < CC) sMean[tid] = Sb[tid * SLD + 62] / (double)TT;
    for (int e = tid; e < CC * LDG; e += 512) sG[e] = 0.0;
    __syncthreads();

    // packed cov_x = (S - T m m^T)/(T-1)
    for (int pi = tid; pi < VECN; pi += 512) {
        int i, j; decodePi(pi, i, j);
        sC[pi] = (Sb[i * SLD + j] - (double)TT * sMean[i] * sMean[j]) / 1999.0;
    }
    __syncthreads();

    // A = W C W^T + eps I, chunks of 8 output columns
    const int jj = tid >> 6, kk = tid & 63;
    for (int j0 = 0; j0 < CC; j0 += 8) {
        const int j = j0 + jj;
        if (kk < CC && j < CC) {
            const float* wr = cw + j * CC;
            double a = 0.0; int idx = kk;
            for (int l = 0; l < kk; ++l) { a += sC[idx] * (double)wr[l]; idx += 61 - l; }
            for (int l = kk; l < CC; ++l) { a += sC[idx] * (double)wr[l]; idx += 1; }
            sU[jj * 64 + kk] = a;    // u_j[k] = (C w_j)[k]
        }
        __syncthreads();
        const int i = kk;
        if (i < CC && j < CC && i <= j) {
            const float* wi = cw + i * CC;
            double a = (i == j) ? 1e-3 : 0.0;
            for (int l = 0; l < CC; ++l) a += (double)wi[l] * sU[jj * 64 + l];
            sG[j * LDG + i] = a;
            sG[i * LDG + j] = a;
        }
        __syncthreads();
    }

    // initial column norms n_k = ||g_k||^2
    if (tid < CC) {
        const double* col = &sG[tid * LDG];
        double n = 0.0;
        for (int i2 = 0; i2 < CC; ++i2) n += col[i2] * col[i2];
        sNorm[tid] = n;
    }
    __syncthreads();

    // one-sided Jacobi: group g (16 lanes) handles pair g each round;
    // lane lt owns rows 4lt..4lt+3 (contiguous, b128)
    const int g = tid >> 4, lt = tid & 15;
    const bool act = (g < NG);
    const int r0 = 4 * lt;

    for (int sweep = 0; sweep < 20; ++sweep) {
        if (tid == 0) sFlag = 0;
        __syncthreads();
        for (int r = 0; r < 61; ++r) {
            if (act) {
                int pq = sPair[r * NG + g];
                int p = pq & 255, q = pq >> 8;
                double2* gp = reinterpret_cast<double2*>(&sG[p * LDG + r0]);
                double2* gq = reinterpret_cast<double2*>(&sG[q * LDG + r0]);
                double2 A0 = gp[0], A1 = gp[1];
                double2 B0 = gq[0], B1 = gq[1];
                double d = A0.x * B0.x + A0.y * B0.y + A1.x * B1.x + A1.y * B1.y;
                d += __shfl_xor(d, 8, 16);
                d += __shfl_xor(d, 4, 16);
                d += __shfl_xor(d, 2, 16);
                d += __shfl_xor(d, 1, 16);
                double np = sNorm[p], nq = sNorm[q];
                if (d * d > np * nq * 1e-12) {
                    // fp32 rotation params (residual ~1e-7*|d| < threshold)
                    float thf = (float)(nq - np) / (2.0f * (float)d);
                    float af = fabsf(thf);
                    float tf = 1.0f / (af + sqrtf(af * af + 1.0f));
                    if (thf < 0.0f) tf = -tf;
                    float cf = rsqrtf(tf * tf + 1.0f);
                    double c = (double)cf, sn = (double)(tf * cf);
                    gp[0] = make_double2(c * A0.x - sn * B0.x, c * A0.y - sn * B0.y);
                    gp[1] = make_double2(c * A1.x - sn * B1.x, c * A1.y - sn * B1.y);
                    gq[0] = make_double2(sn * A0.x + c * B0.x, sn * A0.y + c * B0.y);
                    gq[1] = make_double2(sn * A1.x + c * B1.x, sn * A1.y + c * B1.y);
                    if (lt == 0) {
                        double td = (double)tf * d;
                        sNorm[p] = np - td; sNorm[q] = nq + td;
                        sFlag = 1;
                    }
                }
            }
            __syncthreads();
        }
        int flag = sFlag;
        __syncthreads();
        if (!flag) break;
    }

    // lam_k^2 = ||g_k||^2 ; d_k = log(max(lam,1e-6))/lam^2
    if (tid < CC) {
        const double* col = &sG[tid * LDG];
        double n = 0.0;
        for (int i5 = 0; i5 < CC; ++i5) n += col[i5] * col[i5];
        double lamv = sqrt(n);
        sD[tid] = log(fmax(lamv, 1e-6)) / n;
    }
    __syncthreads();

    float* vb = vecout + (size_t)b * VECN;
    for (int pi = tid; pi < VECN; pi += 512) {
        int i, j; decodePi(pi, i, j);
        double a = 0.0;
        for (int k2 = 0; k2 < CC; ++k2)
            a += sD[k2] * sG[k2 * LDG + i] * sG[k2 * LDG + j];
        vb[pi] = (float)a;
    }
}

// ---------------------------------------------------------------------------
// K3: feat = relu(vec @ proj_w^T + proj_b); logits = feat @ head_w^T + head_b
// grid = B, block = 256 (4-way K-split per hidden unit for latency hiding)
// ---------------------------------------------------------------------------
__global__ __launch_bounds__(256) void k3_mlp(
    const float* __restrict__ vecin, const float* __restrict__ pw,
    const float* __restrict__ pb, const float* __restrict__ hw,
    const float* __restrict__ hb, float* __restrict__ out)
{
    const int b = blockIdx.x;
    const int tid = threadIdx.x;
    __shared__ float sv[VECN];
    __shared__ float sp[4][HID];
    __shared__ float sf[HID];
    for (int k = tid; k < VECN; k += 256) sv[k] = vecin[(size_t)b * VECN + k];
    __syncthreads();
    const int h = tid & 63, pp = tid >> 6;
    const int k0 = (pp * VECN) >> 2, k1 = ((pp + 1) * VECN) >> 2;
    float acc = 0.0f;
    const float* w = pw + (size_t)h * VECN;
    for (int k = k0; k < k1; ++k) acc += sv[k] * w[k];
    sp[pp][h] = acc;
    __syncthreads();
    if (tid < HID) {
        float a = sp[0][tid] + sp[1][tid] + sp[2][tid] + sp[3][tid] + pb[tid];
        sf[tid] = fmaxf(a, 0.0f);
    }
    __syncthreads();
    if (tid < NCLS) {
        float o = hb[tid];
        for (int hh = 0; hh < HID; ++hh) o += sf[hh] * hw[tid * HID + hh];
        out[b * NCLS + tid] = o;
    }
}

// ---------------------------------------------------------------------------
extern "C" void kernel_launch(void* const* d_in, const int* in_sizes, int n_in,
                              void* d_out, int out_size, void* d_ws, size_t ws_size,
                              hipStream_t stream)
{
    const float* x  = (const float*)d_in[0];
    const float* cw = (const float*)d_in[1];
    // d_in[2] = conv bias: cancels in covariance, unused
    const float* pw = (const float*)d_in[3];
    const float* pb = (const float*)d_in[4];
    const float* hw = (const float*)d_in[5];
    const float* hb = (const float*)d_in[6];
    float* out = (float*)d_out;

    // workspace: S [B][64*64] fp64 (8MB), vec [B][VECN] fp32 (2MB)
    double* S = (double*)d_ws;
    float* vec = (float*)(S + (size_t)BB * SLD * 64);

    k1_gram<<<BB, 320, 0, stream>>>(x, S);
    k2_eig<<<BB, 512, 0, stream>>>(S, cw, vec);
    k3_mlp<<<BB, 256, 0, stream>>>(vec, pw, pb, hw, hb, out);
}

// Round 3
// 983.777 us; speedup vs baseline: 1.1920x; 1.1042x over previous
//
#include <hip/hip_runtime.h>
#include <math.h>

// Problem constants
#define CC 62
#define TT 2000
#define BB 256
#define VECN 1953          // C*(C+1)/2
#define HID 64
#define NCLS 3
#define LDG 66             // k2 G column stride (doubles)
#define NG 31              // disjoint pairs per round
#define SLD 64             // S row stride (full 64x64 fp64 block per batch)
#define TTILE2 64          // k1 t-tile (DMA row = 64 lanes)
#define NT1 32             // ceil(TT / TTILE2)
#define LDX 68             // k1 fp32 row stride (272B, 16B-aligned rows)

typedef const unsigned int __attribute__((address_space(1)))* gbl_u32p;
typedef unsigned int __attribute__((address_space(3)))* lds_u32p;

#define K1_WAIT(n) asm volatile("s_waitcnt vmcnt(" #n ")" ::: "memory")

__device__ __forceinline__ void decodePi(int pi, int& i, int& j)
{
    int ii = 0, rem = pi;
    while (rem >= CC - ii) { rem -= (CC - ii); ++ii; }
    i = ii; j = ii + rem;
}

// round-robin (circle method) pair schedule: 31 disjoint pairs, 61 rounds
__device__ __forceinline__ void pairPQ(int r, int k, int& p, int& q)
{
    if (k == 0) { p = 0; q = 1 + (r + 60) % 61; }
    else {
        p = 1 + (r + k - 1) % 61;
        q = 1 + (r + 60 - k) % 61;
    }
    if (p > q) { int t = p; p = q; q = t; }
}

// ---------------------------------------------------------------------------
// K1 (REWRITTEN): fp64 Grammian of x padded with a ones-row (channel 62), so
// S[i][62] = sum_t x_i. One block per batch.
//  - fp32 LDS tiles [2][64][LDX], staged by global_load_lds DMA (coalesced,
//    zero VGPR round-trip), double-buffered with raw s_barrier + counted
//    vmcnt (loads stay in flight across the compute phase).
//  - 8x8 fp64 register tiles: 16 b128 LDS reads per 256 FMA (4x better
//    read:FMA ratio than the old 4x4 fp64 tiling). fp32->fp64 cvt is exact,
//    so the Grammian math is still pure fp64.
//  - 36 chunk-pairs (8 groups of 8 channels): 28 pairs on 16-way t-split
//    slots, 8 pairs on 4 split slots (8-way each) -> 512 threads, waves 4-7
//    run a second (masked) iteration; per-SIMD balance = 3 iter-costs.
// grid = B, block = 512.
// ---------------------------------------------------------------------------
__global__ __launch_bounds__(512) void k1_gram(
    const float* __restrict__ x, double* __restrict__ S)
{
    const int b = blockIdx.x, tid = threadIdx.x;
    const int wid = tid >> 6, lane = tid & 63;

    __shared__ float sX[2][64 * LDX];   // 34.8 KB

    // slot -> pair mapping: slots 19,23,27,31 each serve two pairs (8-way ks)
    const int slot = tid >> 4, ks = tid & 15;
    int pair = 0, myks = ks, kstep = 16;
    {
        int np = 0;
        for (int s2 = 0; s2 < 32; ++s2) {
            bool sp = (s2 >= 16) && ((s2 & 3) == 3);
            if (s2 == slot) {
                if (!sp) { pair = np;             myks = ks;     kstep = 16; }
                else     { pair = np + (ks >> 3); myks = ks & 7; kstep = 8;  }
            }
            np += sp ? 2 : 1;
        }
    }
    int gi = 0, gj = 0;
    { int g2 = 0, rem = pair;
      while (rem >= 8 - g2) { rem -= (8 - g2); ++g2; }
      gi = g2; gj = g2 + rem; }
    const int a0 = 8 * gi, b0 = 8 * gj;

    double acc[8][8];
#pragma unroll
    for (int r = 0; r < 8; ++r)
#pragma unroll
        for (int s = 0; s < 8; ++s) acc[r][s] = 0.0;

    // ones/zero pad rows (both buffers), once — DMA never touches rows 62/63
    if (tid < 128) {
        int bu = tid >> 6, t = tid & 63;
        sX[bu][62 * LDX + t] = 1.0f;
        sX[bu][63 * LDX + t] = 0.0f;
    }
    asm volatile("s_waitcnt lgkmcnt(0)" ::: "memory");

    const float* xb = x + (size_t)b * (CC * TT);

    // DMA one tile: wave w issues rows c = w, w+8, ... (w<6: 8 instrs, else 7)
    auto issueTile = [&](int buf, int tile) {
        const int t0 = tile * TTILE2;
        for (int c = wid; c < CC; c += 8) {
            if (t0 + lane < TT) {
                const float* gp = xb + (size_t)c * TT + t0 + lane;
                __builtin_amdgcn_global_load_lds(
                    (gbl_u32p)gp, (lds_u32p)&sX[buf][c * LDX], 4, 0, 0);
            }
        }
    };

    issueTile(0, 0);
    for (int tile = 0; tile < NT1; ++tile) {
        const int cur = tile & 1;
        __builtin_amdgcn_s_barrier();            // prev compute done: buf cur^1 free
        if (tile + 1 < NT1) {
            issueTile(cur ^ 1, tile + 1);
            if (wid < 6) K1_WAIT(8); else K1_WAIT(7);   // cur-tile loads done
        } else {
            K1_WAIT(0);
        }
        __builtin_amdgcn_sched_barrier(0);
        __builtin_amdgcn_s_barrier();            // all waves' cur loads visible
        const float* xt = &sX[cur][0];
        const int nq = min(16, (TT - tile * TTILE2) >> 2);
        for (int m = myks; m < nq; m += kstep) {
            float4 af[8], bf[8];
#pragma unroll
            for (int r = 0; r < 8; ++r)
                af[r] = *reinterpret_cast<const float4*>(&xt[(a0 + r) * LDX + 4 * m]);
#pragma unroll
            for (int r = 0; r < 8; ++r)
                bf[r] = *reinterpret_cast<const float4*>(&xt[(b0 + r) * LDX + 4 * m]);
#pragma unroll
            for (int k = 0; k < 4; ++k) {
                double ad[8], bd[8];
#pragma unroll
                for (int r = 0; r < 8; ++r) ad[r] = (double)((&af[r].x)[k]);
#pragma unroll
                for (int s = 0; s < 8; ++s) bd[s] = (double)((&bf[s].x)[k]);
#pragma unroll
                for (int r = 0; r < 8; ++r)
#pragma unroll
                    for (int s = 0; s < 8; ++s)
                        acc[r][s] += ad[r] * bd[s];
            }
        }
    }

    // reduce across the slot's ks lanes (16-wide, or 8-wide for split slots)
    const int red0 = (kstep == 16) ? 8 : 4;
#pragma unroll
    for (int r = 0; r < 8; ++r)
#pragma unroll
        for (int s = 0; s < 8; ++s) {
            double v = acc[r][s];
            for (int o = red0; o > 0; o >>= 1)
                v += __shfl_xor(v, o, 16);
            acc[r][s] = v;
        }

    if (myks == 0) {
        double* Sb = S + (size_t)b * (SLD * 64);
#pragma unroll
        for (int r = 0; r < 8; ++r)
#pragma unroll
            for (int s = 0; s < 8; ++s)
                Sb[(a0 + r) * SLD + (b0 + s)] = acc[r][s];
    }
}

// ---------------------------------------------------------------------------
// K2: assemble cov_x, A = W cov_x W^T + eps I, one-sided Jacobi, log-map.
// Round-0 structure (512 thr, 16-lane groups, LDG=66) with ONE change:
// the dot-product reduce is now fp32 XOR-butterfly via 2 DPP quad_perm steps
// (VALU pipe) + 2 ds_swizzle steps — replaces 8 ds_bpermute/wave/round of
// the fp64 __shfl_xor chain. Butterfly keeps d bitwise-identical across the
// 16 lanes (no divergence on the rotate branch). fp32 d error ~1% of the
// rotation threshold.
// grid = B, block = 512. 1 barrier/round. Lane lt owns rows 4lt..4lt+3.
// ---------------------------------------------------------------------------
__global__ __launch_bounds__(512) void k2_eig(
    const double* __restrict__ S, const float* __restrict__ cw,
    float* __restrict__ vecout)
{
    const int b = blockIdx.x, tid = threadIdx.x;

    __shared__ double sG[CC * LDG];    // column-major, rows padded to 64+ w/ 0
    __shared__ double sC[VECN];        // packed upper-tri cov_x
    __shared__ double sU[8 * 64];
    __shared__ double sNorm[64];
    __shared__ double sD[64];
    __shared__ double sMean[64];
    __shared__ int    sPair[61 * NG];
    __shared__ int    sFlag;

    const double* Sb = S + (size_t)b * (SLD * 64);

    for (int e = tid; e < 61 * NG; e += 512) {
        int r = e / NG, k = e - r * NG;
        int p, q; pairPQ(r, k, p, q);
        sPair[e] = p | (q << 8);
    }
    if (tid < CC) sMean[tid] = Sb[tid * SLD + 62] / (double)TT;
    for (int e = tid; e < CC * LDG; e += 512) sG[e] = 0.0;
    __syncthreads();

    // packed cov_x = (S - T m m^T)/(T-1)
    for (int pi = tid; pi < VECN; pi += 512) {
        int i, j; decodePi(pi, i, j);
        sC[pi] = (Sb[i * SLD + j] - (double)TT * sMean[i] * sMean[j]) / 1999.0;
    }
    __syncthreads();

    // A = W C W^T + eps I, chunks of 8 output columns
    const int jj = tid >> 6, kk = tid & 63;
    for (int j0 = 0; j0 < CC; j0 += 8) {
        const int j = j0 + jj;
        if (kk < CC && j < CC) {
            const float* wr = cw + j * CC;
            double a = 0.0; int idx = kk;
            for (int l = 0; l < kk; ++l) { a += sC[idx] * (double)wr[l]; idx += 61 - l; }
            for (int l = kk; l < CC; ++l) { a += sC[idx] * (double)wr[l]; idx += 1; }
            sU[jj * 64 + kk] = a;    // u_j[k] = (C w_j)[k]
        }
        __syncthreads();
        const int i = kk;
        if (i < CC && j < CC && i <= j) {
            const float* wi = cw + i * CC;
            double a = (i == j) ? 1e-3 : 0.0;
            for (int l = 0; l < CC; ++l) a += (double)wi[l] * sU[jj * 64 + l];
            sG[j * LDG + i] = a;
            sG[i * LDG + j] = a;
        }
        __syncthreads();
    }

    // initial column norms n_k = ||g_k||^2
    if (tid < CC) {
        const double* col = &sG[tid * LDG];
        double n = 0.0;
        for (int i2 = 0; i2 < CC; ++i2) n += col[i2] * col[i2];
        sNorm[tid] = n;
    }
    __syncthreads();

    // one-sided Jacobi: group g (16 lanes) handles pair g each round;
    // lane lt owns rows 4lt..4lt+3 (contiguous, b128)
    const int g = tid >> 4, lt = tid & 15;
    const bool act = (g < NG);
    const int r0 = 4 * lt;

    for (int sweep = 0; sweep < 20; ++sweep) {
        if (tid == 0) sFlag = 0;
        __syncthreads();
        for (int r = 0; r < 61; ++r) {
            if (act) {
                int pq = sPair[r * NG + g];
                int p = pq & 255, q = pq >> 8;
                double2* gp = reinterpret_cast<double2*>(&sG[p * LDG + r0]);
                double2* gq = reinterpret_cast<double2*>(&sG[q * LDG + r0]);
                double2 A0 = gp[0], A1 = gp[1];
                double2 B0 = gq[0], B1 = gq[1];
                double dd64 = A0.x * B0.x + A0.y * B0.y + A1.x * B1.x + A1.y * B1.y;
                // fp32 XOR-butterfly reduce over the 16-lane group:
                // xor1, xor2 via DPP quad_perm (VALU); xor4, xor8 via ds_swizzle.
                float df = (float)dd64;
                { int t2 = __builtin_amdgcn_mov_dpp(__float_as_int(df), 0xB1, 0xF, 0xF, true);
                  df += __int_as_float(t2); }   // lane ^= 1
                { int t2 = __builtin_amdgcn_mov_dpp(__float_as_int(df), 0x4E, 0xF, 0xF, true);
                  df += __int_as_float(t2); }   // lane ^= 2
                { int t2 = __builtin_amdgcn_ds_swizzle(__float_as_int(df), 0x101F);
                  df += __int_as_float(t2); }   // lane ^= 4
                { int t2 = __builtin_amdgcn_ds_swizzle(__float_as_int(df), 0x201F);
                  df += __int_as_float(t2); }   // lane ^= 8
                double d = (double)df;
                double np = sNorm[p], nq = sNorm[q];
                if (d * d > np * nq * 1e-12) {
                    float thf = (float)(nq - np) / (2.0f * df);
                    float af = fabsf(thf);
                    float tf = 1.0f / (af + sqrtf(af * af + 1.0f));
                    if (thf < 0.0f) tf = -tf;
                    float cf = rsqrtf(tf * tf + 1.0f);
                    double c = (double)cf, sn = (double)(tf * cf);
                    gp[0] = make_double2(c * A0.x - sn * B0.x, c * A0.y - sn * B0.y);
                    gp[1] = make_double2(c * A1.x - sn * B1.x, c * A1.y - sn * B1.y);
                    gq[0] = make_double2(sn * A0.x + c * B0.x, sn * A0.y + c * B0.y);
                    gq[1] = make_double2(sn * A1.x + c * B1.x, sn * A1.y + c * B1.y);
                    if (lt == 0) {
                        double td = (double)tf * d;
                        sNorm[p] = np - td; sNorm[q] = nq + td;
                        sFlag = 1;
                    }
                }
            }
            __syncthreads();
        }
        int flag = sFlag;
        __syncthreads();
        if (!flag) break;
    }

    // lam_k^2 = ||g_k||^2 ; d_k = log(max(lam,1e-6))/lam^2
    if (tid < CC) {
        const double* col = &sG[tid * LDG];
        double n = 0.0;
        for (int i5 = 0; i5 < CC; ++i5) n += col[i5] * col[i5];
        double lamv = sqrt(n);
        sD[tid] = log(fmax(lamv, 1e-6)) / n;
    }
    __syncthreads();

    float* vb = vecout + (size_t)b * VECN;
    for (int pi = tid; pi < VECN; pi += 512) {
        int i, j; decodePi(pi, i, j);
        double a = 0.0;
        for (int k2 = 0; k2 < CC; ++k2)
            a += sD[k2] * sG[k2 * LDG + i] * sG[k2 * LDG + j];
        vb[pi] = (float)a;
    }
}

// ---------------------------------------------------------------------------
// K3 (REWRITTEN): coalesced weights. Each wave owns 16 hidden units; all 64
// lanes split the K dimension (consecutive addresses -> coalesced pw reads)
// and shuffle-reduce. grid = B, block = 256.
// ---------------------------------------------------------------------------
__global__ __launch_bounds__(256) void k3_mlp(
    const float* __restrict__ vecin, const float* __restrict__ pw,
    const float* __restrict__ pb, const float* __restrict__ hw,
    const float* __restrict__ hb, float* __restrict__ out)
{
    const int b = blockIdx.x;
    const int tid = threadIdx.x;
    const int wid = tid >> 6, lane = tid & 63;
    __shared__ float sv[VECN];
    __shared__ float sf[HID];
    for (int k = tid; k < VECN; k += 256) sv[k] = vecin[(size_t)b * VECN + k];
    __syncthreads();
    for (int hh = 0; hh < 16; ++hh) {
        const int h = wid * 16 + hh;
        const float* w = pw + (size_t)h * VECN;
        float a = 0.0f;
        for (int k = lane; k < VECN; k += 64) a += sv[k] * w[k];
        a += __shfl_xor(a, 32); a += __shfl_xor(a, 16); a += __shfl_xor(a, 8);
        a += __shfl_xor(a, 4);  a += __shfl_xor(a, 2);  a += __shfl_xor(a, 1);
        if (lane == 0) sf[h] = fmaxf(a + pb[h], 0.0f);
    }
    __syncthreads();
    if (tid < NCLS) {
        float o = hb[tid];
        for (int hh = 0; hh < HID; ++hh) o += sf[hh] * hw[tid * HID + hh];
        out[b * NCLS + tid] = o;
    }
}

// ---------------------------------------------------------------------------
extern "C" void kernel_launch(void* const* d_in, const int* in_sizes, int n_in,
                              void* d_out, int out_size, void* d_ws, size_t ws_size,
                              hipStream_t stream)
{
    const float* x  = (const float*)d_in[0];
    const float* cw = (const float*)d_in[1];
    // d_in[2] = conv bias: cancels in covariance, unused
    const float* pw = (const float*)d_in[3];
    const float* pb = (const float*)d_in[4];
    const float* hw = (const float*)d_in[5];
    const float* hb = (const float*)d_in[6];
    float* out = (float*)d_out;

    // workspace: S [B][64*64] fp64 (8MB), vec [B][VECN] fp32 (2MB)
    double* S = (double*)d_ws;
    float* vec = (float*)(S + (size_t)BB * SLD * 64);

    k1_gram<<<BB, 512, 0, stream>>>(x, S);
    k2_eig<<<BB, 512, 0, stream>>>(S, cw, vec);
    k3_mlp<<<BB, 256, 0, stream>>>(vec, pw, pb, hw, hb, out);
}

// Round 4
// 805.246 us; speedup vs baseline: 1.4563x; 1.2217x over previous
//
#include <hip/hip_runtime.h>
#include <math.h>

// Problem constants
#define CC 62
#define TT 2000
#define BB 256
#define VECN 1953          // C*(C+1)/2
#define HID 64
#define NCLS 3
#define NG 31              // disjoint Jacobi pairs per round
#define LDG 66             // G column stride (doubles)
#define LDX 68             // x-tile row stride (floats); 68%32=4 -> bank math below
#define XBUF (64 * LDX)    // floats per x-tile buffer (4352)
#define NT1 32             // ceil(TT / 64)
#define SLD 64             // S row stride (doubles)

typedef const unsigned int __attribute__((address_space(1)))* gbl_u32p;
typedef unsigned int __attribute__((address_space(3)))* lds_u32p;

#define WAITV(n) asm volatile("s_waitcnt vmcnt(" #n ")" ::: "memory")

__device__ __forceinline__ void decodePi(int pi, int& i, int& j)
{
    int ii = 0, rem = pi;
    while (rem >= CC - ii) { rem -= (CC - ii); ++ii; }
    i = ii; j = ii + rem;
}

// round-robin (circle method) pair schedule: 31 disjoint pairs, 61 rounds
__device__ __forceinline__ void pairPQ(int r, int k, int& p, int& q)
{
    if (k == 0) { p = 0; q = 1 + (r + 60) % 61; }
    else {
        p = 1 + (r + k - 1) % 61;
        q = 1 + (r + 60 - k) % 61;
    }
    if (p > q) { int t = p; p = q; q = t; }
}

// ---------------------------------------------------------------------------
// FUSED: Grammian -> cov -> A=WCW^T+epsI -> one-sided Jacobi -> log-map ->
// triu-vec -> MLP head. ONE dispatch, grid=B, block=576 (9 waves).
// Eliminates two kernel boundaries + the S(8MB)/vec(2MB) HBM round-trips —
// the ~420us non-k2 residual has been invariant across three k1 rewrites,
// pointing at inter-dispatch overhead, not kernel compute.
//
// Phase A (Grammian, ~35us predicted): x padded with ones-row (chan 62) so
//   S[i][62]=sum_t x_i. 136 4x4-channel pair-tiles x 4-lane t-split = 544
//   active lanes; acc=16 fp64 (32 VGPR, spill-free). fp32 LDS tiles
//   [2][64][LDX] staged by global_load_lds DMA, double-buffered, raw
//   s_barrier + counted vmcnt. DMA source is chunk-XOR pre-swizzled
//   (lane loads t = t0 + 4*((l>>2)^p(c)) + (l&3), p(c)=c>>3) so LDS stays
//   linear (global_load_lds constraint) while reads at chunk m^p(row) are
//   conflict-free: bank = 16(g&1)+4r+4((m')^(g>>1)) mod 32 — for fixed
//   (r, m-phase), equal banks imply equal group => same address (broadcast).
// Phase B (Jacobi, unchanged from the 563us-proven round-3 k2): 16-lane
//   groups, fp64 apply, fp32 DPP+ds_swizzle butterfly reduce, cached norms.
// Phase C (MLP): vec in LDS, coalesced pw reads, shuffle reduce; the only
//   global write is out[b][0..2].
// LDS overlays: region sA hosts sX(34816B) -> sS(32768B) -> sG(32736B);
// sC(15624B) -> sVec(7812B). Total ~60.6KB <= 64KB static.
// ---------------------------------------------------------------------------
__global__ __launch_bounds__(576) void fused(
    const float* __restrict__ x, const float* __restrict__ cw,
    const float* __restrict__ pw, const float* __restrict__ pbias,
    const float* __restrict__ hw, const float* __restrict__ hb,
    float* __restrict__ out)
{
    const int b = blockIdx.x, tid = threadIdx.x;
    const int wid = tid >> 6, lane = tid & 63;

    __shared__ __align__(16) double sA[4352];   // 34816 B: sX | sS | sG
    __shared__ __align__(16) double sC[VECN];   // 15624 B: cov | sVec
    __shared__ double sU[9 * 64];
    __shared__ double sNorm[64];
    __shared__ double sD[64];
    __shared__ double sMean[64];
    __shared__ unsigned short sPair[61 * NG];
    __shared__ int    sFlag;
    __shared__ float  sF[HID];

    float*  sX   = reinterpret_cast<float*>(sA);
    double* sS   = sA;
    double* sG   = sA;
    float*  sVec = reinterpret_cast<float*>(sC);

    // ---------------- Phase A: Grammian ----------------
    const int slot = tid >> 2, myks = tid & 3;
    const bool actA = (slot < 136);
    int gi = 0, gj = 0;
    if (actA) {
        int g = 0, rem = slot;
        while (rem >= 16 - g) { rem -= (16 - g); ++g; }
        gi = g; gj = g + rem;
    }
    const int a0 = 4 * gi, b0 = 4 * gj;
    const int pA = gi >> 1, pB = gj >> 1;   // (4g+r)>>3 for r<4

    double acc[4][4];
#pragma unroll
    for (int r = 0; r < 4; ++r)
#pragma unroll
        for (int c = 0; c < 4; ++c) acc[r][c] = 0.0;

    // Jacobi pair table (region untouched by phase A LDS)
    for (int e = tid; e < 61 * NG; e += 576) {
        int r = e / NG, k = e - r * NG;
        int p, q; pairPQ(r, k, p, q);
        sPair[e] = (unsigned short)(p | (q << 8));
    }
    // pad rows: 62 = ones (mean trick), 63 = zero; both buffers, once.
    if (tid < 128) {
        int bu = tid >> 6, t = tid & 63;
        sX[bu * XBUF + 62 * LDX + t] = 1.0f;
        sX[bu * XBUF + 63 * LDX + t] = 0.0f;
    }
    __syncthreads();

    const float* xb = x + (size_t)b * (CC * TT);

    // DMA one tile: wave w issues rows c = w, w+9, ... (w<8: 7 rows, w=8: 6).
    // Global source chunk-XOR pre-swizzled; LDS dest linear (uniform base).
    auto issueTile = [&](int buf, int tile) {
        const int t0 = tile * 64;
        for (int c = wid; c < CC; c += 9) {
            const int ps = c >> 3;
            const int tt = 4 * ((lane >> 2) ^ ps) + (lane & 3);
            if (t0 + tt < TT) {
                const float* gp = xb + (size_t)c * TT + t0 + tt;
                __builtin_amdgcn_global_load_lds(
                    (gbl_u32p)gp, (lds_u32p)&sX[buf * XBUF + c * LDX], 4, 0, 0);
            }
        }
    };

    issueTile(0, 0);
    for (int tile = 0; tile < NT1; ++tile) {
        const int cur = tile & 1;
        __builtin_amdgcn_s_barrier();        // prev compute done: buf cur^1 free
        if (tile + 1 < NT1) {
            issueTile(cur ^ 1, tile + 1);
            if (wid < 8) WAITV(7); else WAITV(6);   // cur-tile loads landed
        } else {
            WAITV(0);
        }
        __builtin_amdgcn_sched_barrier(0);
        __builtin_amdgcn_s_barrier();        // all waves' cur loads visible
        if (actA) {
            const float* xt = &sX[cur * XBUF];
            const int nq = min(16, (TT - tile * 64) >> 2);
            for (int m = myks; m < nq; m += 4) {
                const int ca = 4 * (m ^ pA), cb = 4 * (m ^ pB);
                float4 af[4], bf[4];
#pragma unroll
                for (int r = 0; r < 4; ++r)
                    af[r] = *reinterpret_cast<const float4*>(&xt[(a0 + r) * LDX + ca]);
#pragma unroll
                for (int r = 0; r < 4; ++r)
                    bf[r] = *reinterpret_cast<const float4*>(&xt[(b0 + r) * LDX + cb]);
#pragma unroll
                for (int k = 0; k < 4; ++k) {
                    double ad[4], bd[4];
#pragma unroll
                    for (int r = 0; r < 4; ++r) ad[r] = (double)((&af[r].x)[k]);
#pragma unroll
                    for (int s = 0; s < 4; ++s) bd[s] = (double)((&bf[s].x)[k]);
#pragma unroll
                    for (int r = 0; r < 4; ++r)
#pragma unroll
                        for (int s = 0; s < 4; ++s)
                            acc[r][s] += ad[r] * bd[s];
                }
            }
        }
    }

    // 4-lane t-split reduce (registers only), then sS overlay of sX
#pragma unroll
    for (int r = 0; r < 4; ++r)
#pragma unroll
        for (int c = 0; c < 4; ++c) {
            double v = acc[r][c];
            v += __shfl_xor(v, 1, 4);
            v += __shfl_xor(v, 2, 4);
            acc[r][c] = v;
        }
    __syncthreads();                 // all sX reads complete before overlay
    if (actA && myks == 0) {
#pragma unroll
        for (int r = 0; r < 4; ++r)
#pragma unroll
            for (int c = 0; c < 4; ++c)
                sS[(a0 + r) * SLD + (b0 + c)] = acc[r][c];
    }
    __syncthreads();

    // ---------------- Phase B: cov -> A -> Jacobi -> log-map ----------------
    if (tid < CC) sMean[tid] = sS[tid * SLD + 62] / (double)TT;
    __syncthreads();

    // packed cov_x = (S - T m m^T)/(T-1)
    for (int pi = tid; pi < VECN; pi += 576) {
        int i, j; decodePi(pi, i, j);
        sC[pi] = (sS[i * SLD + j] - (double)TT * sMean[i] * sMean[j]) / 1999.0;
    }
    __syncthreads();

    // sS dead -> zero sG (overlay)
    for (int e = tid; e < CC * LDG; e += 576) sG[e] = 0.0;
    __syncthreads();

    // A = W C W^T + eps I, chunks of 9 output columns
    const int jj = tid >> 6, kk = tid & 63;
    for (int j0 = 0; j0 < CC; j0 += 9) {
        const int j = j0 + jj;
        if (kk < CC && j < CC) {
            const float* wr = cw + j * CC;
            double a = 0.0; int idx = kk;
            for (int l = 0; l < kk; ++l) { a += sC[idx] * (double)wr[l]; idx += 61 - l; }
            for (int l = kk; l < CC; ++l) { a += sC[idx] * (double)wr[l]; idx += 1; }
            sU[jj * 64 + kk] = a;    // u_j[k] = (C w_j)[k]
        }
        __syncthreads();
        const int i = kk;
        if (i < CC && j < CC && i <= j) {
            const float* wi = cw + i * CC;
            double a = (i == j) ? 1e-3 : 0.0;
            for (int l = 0; l < CC; ++l) a += (double)wi[l] * sU[jj * 64 + l];
            sG[j * LDG + i] = a;
            sG[i * LDG + j] = a;
        }
        __syncthreads();
    }

    // initial column norms n_k = ||g_k||^2
    if (tid < CC) {
        const double* col = &sG[tid * LDG];
        double n = 0.0;
        for (int i2 = 0; i2 < CC; ++i2) n += col[i2] * col[i2];
        sNorm[tid] = n;
    }
    __syncthreads();

    // one-sided Jacobi: group g (16 lanes) handles pair g each round;
    // lane lt owns rows 4lt..4lt+3 (contiguous, b128). [round-3 proven body]
    const int g = tid >> 4, lt = tid & 15;
    const bool actJ = (g < NG);
    const int r0 = 4 * lt;

    for (int sweep = 0; sweep < 20; ++sweep) {
        if (tid == 0) sFlag = 0;
        __syncthreads();
        for (int r = 0; r < 61; ++r) {
            if (actJ) {
                int pq = sPair[r * NG + g];
                int p = pq & 255, q = pq >> 8;
                double2* gp = reinterpret_cast<double2*>(&sG[p * LDG + r0]);
                double2* gq = reinterpret_cast<double2*>(&sG[q * LDG + r0]);
                double2 A0 = gp[0], A1 = gp[1];
                double2 B0 = gq[0], B1 = gq[1];
                double dd64 = A0.x * B0.x + A0.y * B0.y + A1.x * B1.x + A1.y * B1.y;
                // fp32 XOR-butterfly reduce: xor1/xor2 via DPP quad_perm
                // (VALU pipe), xor4/xor8 via ds_swizzle. Bitwise-identical d
                // across the 16 lanes -> no divergence on the rotate branch.
                float df = (float)dd64;
                { int t2 = __builtin_amdgcn_mov_dpp(__float_as_int(df), 0xB1, 0xF, 0xF, true);
                  df += __int_as_float(t2); }   // lane ^= 1
                { int t2 = __builtin_amdgcn_mov_dpp(__float_as_int(df), 0x4E, 0xF, 0xF, true);
                  df += __int_as_float(t2); }   // lane ^= 2
                { int t2 = __builtin_amdgcn_ds_swizzle(__float_as_int(df), 0x101F);
                  df += __int_as_float(t2); }   // lane ^= 4
                { int t2 = __builtin_amdgcn_ds_swizzle(__float_as_int(df), 0x201F);
                  df += __int_as_float(t2); }   // lane ^= 8
                double d = (double)df;
                double np = sNorm[p], nq = sNorm[q];
                if (d * d > np * nq * 1e-12) {
                    float thf = (float)(nq - np) / (2.0f * df);
                    float af2 = fabsf(thf);
                    float tf = 1.0f / (af2 + sqrtf(af2 * af2 + 1.0f));
                    if (thf < 0.0f) tf = -tf;
                    float cf = rsqrtf(tf * tf + 1.0f);
                    double c = (double)cf, sn = (double)(tf * cf);
                    gp[0] = make_double2(c * A0.x - sn * B0.x, c * A0.y - sn * B0.y);
                    gp[1] = make_double2(c * A1.x - sn * B1.x, c * A1.y - sn * B1.y);
                    gq[0] = make_double2(sn * A0.x + c * B0.x, sn * A0.y + c * B0.y);
                    gq[1] = make_double2(sn * A1.x + c * B1.x, sn * A1.y + c * B1.y);
                    if (lt == 0) {
                        double td = (double)tf * d;
                        sNorm[p] = np - td; sNorm[q] = nq + td;
                        sFlag = 1;
                    }
                }
            }
            __syncthreads();
        }
        int flag = sFlag;
        __syncthreads();
        if (!flag) break;
    }

    // lam_k^2 = ||g_k||^2 ; d_k = log(max(lam,1e-6))/lam^2
    if (tid < CC) {
        const double* col = &sG[tid * LDG];
        double n = 0.0;
        for (int i5 = 0; i5 < CC; ++i5) n += col[i5] * col[i5];
        double lamv = sqrt(n);
        sD[tid] = log(fmax(lamv, 1e-6)) / n;
    }
    __syncthreads();

    // triu vectorization into LDS (sVec overlays dead sC)
    for (int pi = tid; pi < VECN; pi += 576) {
        int i, j; decodePi(pi, i, j);
        double a = 0.0;
        for (int k2 = 0; k2 < CC; ++k2)
            a += sD[k2] * sG[k2 * LDG + i] * sG[k2 * LDG + j];
        sVec[pi] = (float)a;
    }
    __syncthreads();

    // ---------------- Phase C: MLP head ----------------
    if (wid < 8) {
        for (int hh = 0; hh < 8; ++hh) {
            const int h = wid * 8 + hh;
            const float* w = pw + (size_t)h * VECN;
            float a = 0.0f;
            for (int k = lane; k < VECN; k += 64) a += sVec[k] * w[k];
            a += __shfl_xor(a, 32); a += __shfl_xor(a, 16); a += __shfl_xor(a, 8);
            a += __shfl_xor(a, 4);  a += __shfl_xor(a, 2);  a += __shfl_xor(a, 1);
            if (lane == 0) sF[h] = fmaxf(a + pbias[h], 0.0f);
        }
    }
    __syncthreads();
    if (tid < NCLS) {
        float o = hb[tid];
        for (int hh = 0; hh < HID; ++hh) o += sF[hh] * hw[tid * HID + hh];
        out[b * NCLS + tid] = o;
    }
}

// ---------------------------------------------------------------------------
extern "C" void kernel_launch(void* const* d_in, const int* in_sizes, int n_in,
                              void* d_out, int out_size, void* d_ws, size_t ws_size,
                              hipStream_t stream)
{
    const float* x  = (const float*)d_in[0];
    const float* cw = (const float*)d_in[1];
    // d_in[2] = conv bias: cancels in covariance, unused
    const float* pw = (const float*)d_in[3];
    const float* pb = (const float*)d_in[4];
    const float* hw = (const float*)d_in[5];
    const float* hb = (const float*)d_in[6];
    float* out = (float*)d_out;

    // single fused dispatch; workspace unused
    fused<<<BB, 576, 0, stream>>>(x, cw, pw, pb, hw, hb, out);
}

// Round 6
// 690.350 us; speedup vs baseline: 1.6987x; 1.1664x over previous
//
#include <hip/hip_runtime.h>
#include <math.h>

// Problem constants
#define CC 62
#define TT 2000
#define BB 256
#define VECN 1953          // C*(C+1)/2
#define HID 64
#define NCLS 3
#define NG 31              // disjoint Jacobi pairs per round
#define LDX 68             // x-tile row stride (floats)
#define XBUF (64 * LDX)    // floats per x-tile buffer (4352)
#define NT1 32             // ceil(TT / 64)
#define SLD 64             // S row stride (doubles)
#define LDGF 68            // fp32 G column stride (floats, 272B -> 16B aligned)

typedef const unsigned int __attribute__((address_space(1)))* gbl_u32p;
typedef unsigned int __attribute__((address_space(3)))* lds_u32p;

#define WAITV(n) asm volatile("s_waitcnt vmcnt(" #n ")" ::: "memory")

__device__ __forceinline__ void decodePi(int pi, int& i, int& j)
{
    int ii = 0, rem = pi;
    while (rem >= CC - ii) { rem -= (CC - ii); ++ii; }
    i = ii; j = ii + rem;
}

// round-robin (circle method) pair schedule: 31 disjoint pairs, 61 rounds
__device__ __forceinline__ void pairPQ(int r, int k, int& p, int& q)
{
    if (k == 0) { p = 0; q = 1 + (r + 60) % 61; }
    else {
        p = 1 + (r + k - 1) % 61;
        q = 1 + (r + 60 - k) % 61;
    }
    if (p > q) { int t = p; p = q; q = t; }
}

// ---------------------------------------------------------------------------
// FUSED (round 5 resubmit — round 5 bench was an infra failure, kernel never
// ran): Grammian -> cov -> A=WCW^T+epsI -> one-sided Jacobi -> log-map ->
// triu-vec -> MLP head. ONE dispatch, grid=B, block=576 (9 waves).
//
// Changes vs round 4 (fusion-proven, 710us):
//  1. Phase A accumulates products in fp32 (per-tile partial, <=16 products)
//     and promotes to fp64 once per tile. Products of fp32 inputs need no
//     fp64 FMA; error ~2.5e-4 on S (|S|~2000) -> ~1.2e-7 on cov. Removes the
//     fp64-FMA issue bound (272K cy -> ~55K cy) and all per-k cvts.
//  2. Jacobi G stored in fp32 (LDS traffic and rotate-VALU both halve:
//     1 ds_read_b128 per column per lane instead of 2). Rotation threshold
//     |d| > 1e-6*lam_p*lam_q sits 16x above fp32 dot noise (6e-8) -> same
//     convergence. Norm cache stays fp64; final lambda/log-map recomputed
//     in fp64 from fp32 G. LDS bonus: fp32 G (16.9KB) overlays dead sS.
//  3. Butterfly reduce fully on VALU: quad_perm xor1/xor2 + row_half_mirror
//     (=xor4 on quad-uniform values) + row_mirror (=xor8) -> zero LDS instrs
//     in the reduce, d still bitwise-uniform across the 16-lane group.
//
// LDS overlays: sA region hosts sX(34816B) -> sS(32768B) -> sGf(16864B);
// sC(15624B) -> sVec. Total ~60.6KB static.
// ---------------------------------------------------------------------------
__global__ __launch_bounds__(576) void fused(
    const float* __restrict__ x, const float* __restrict__ cw,
    const float* __restrict__ pw, const float* __restrict__ pbias,
    const float* __restrict__ hw, const float* __restrict__ hb,
    float* __restrict__ out)
{
    const int b = blockIdx.x, tid = threadIdx.x;
    const int wid = tid >> 6, lane = tid & 63;

    __shared__ __align__(16) double sA[4352];   // 34816 B: sX | sS | sGf
    __shared__ __align__(16) double sC[VECN];   // 15624 B: cov | sVec
    __shared__ double sU[9 * 64];
    __shared__ double sNorm[64];
    __shared__ double sD[64];
    __shared__ double sMean[64];
    __shared__ unsigned short sPair[61 * NG];
    __shared__ int    sFlag;
    __shared__ float  sF[HID];

    float*  sX   = reinterpret_cast<float*>(sA);
    double* sS   = sA;
    float*  sGf  = reinterpret_cast<float*>(sA);   // overlays dead sS
    float*  sVec = reinterpret_cast<float*>(sC);

    // ---------------- Phase A: Grammian ----------------
    const int slot = tid >> 2, myks = tid & 3;
    const bool actA = (slot < 136);
    int gi = 0, gj = 0;
    if (actA) {
        int g = 0, rem = slot;
        while (rem >= 16 - g) { rem -= (16 - g); ++g; }
        gi = g; gj = g + rem;
    }
    const int a0 = 4 * gi, b0 = 4 * gj;
    const int pA = gi >> 1, pB = gj >> 1;   // (4g+r)>>3 for r<4

    double acc[4][4];
    float  accf[4][4];
#pragma unroll
    for (int r = 0; r < 4; ++r)
#pragma unroll
        for (int c = 0; c < 4; ++c) { acc[r][c] = 0.0; accf[r][c] = 0.0f; }

    // Jacobi pair table (region untouched by phase A LDS)
    for (int e = tid; e < 61 * NG; e += 576) {
        int r = e / NG, k = e - r * NG;
        int p, q; pairPQ(r, k, p, q);
        sPair[e] = (unsigned short)(p | (q << 8));
    }
    // pad rows: 62 = ones (mean trick), 63 = zero; both buffers, once.
    if (tid < 128) {
        int bu = tid >> 6, t = tid & 63;
        sX[bu * XBUF + 62 * LDX + t] = 1.0f;
        sX[bu * XBUF + 63 * LDX + t] = 0.0f;
    }
    __syncthreads();

    const float* xb = x + (size_t)b * (CC * TT);

    // DMA one tile: wave w issues rows c = w, w+9, ... (w<8: 7 rows, w=8: 6).
    // Global source chunk-XOR pre-swizzled (p(c)=c>>3); LDS dest linear
    // (global_load_lds constraint). LDS chunk c' of row c holds global chunk
    // c'^p(c), so compute reads chunk m^p(row) to get global chunk m.
    auto issueTile = [&](int buf, int tile) {
        const int t0 = tile * 64;
        for (int c = wid; c < CC; c += 9) {
            const int ps = c >> 3;
            const int tt = 4 * ((lane >> 2) ^ ps) + (lane & 3);
            if (t0 + tt < TT) {
                const float* gp = xb + (size_t)c * TT + t0 + tt;
                __builtin_amdgcn_global_load_lds(
                    (gbl_u32p)gp, (lds_u32p)&sX[buf * XBUF + c * LDX], 4, 0, 0);
            }
        }
    };

    issueTile(0, 0);
    for (int tile = 0; tile < NT1; ++tile) {
        const int cur = tile & 1;
        __builtin_amdgcn_s_barrier();        // prev compute done: buf cur^1 free
        if (tile + 1 < NT1) {
            issueTile(cur ^ 1, tile + 1);
            if (wid < 8) WAITV(7); else WAITV(6);   // cur-tile loads landed
        } else {
            WAITV(0);
        }
        __builtin_amdgcn_sched_barrier(0);
        __builtin_amdgcn_s_barrier();        // all waves' cur loads visible
        if (actA) {
            const float* xt = &sX[cur * XBUF];
            const int nq = min(16, (TT - tile * 64) >> 2);
            for (int m = myks; m < nq; m += 4) {
                const int ca = 4 * (m ^ pA), cb = 4 * (m ^ pB);
                float4 af[4], bf[4];
#pragma unroll
                for (int r = 0; r < 4; ++r)
                    af[r] = *reinterpret_cast<const float4*>(&xt[(a0 + r) * LDX + ca]);
#pragma unroll
                for (int r = 0; r < 4; ++r)
                    bf[r] = *reinterpret_cast<const float4*>(&xt[(b0 + r) * LDX + cb]);
#pragma unroll
                for (int k = 0; k < 4; ++k) {
#pragma unroll
                    for (int r = 0; r < 4; ++r)
#pragma unroll
                        for (int s = 0; s < 4; ++s)
                            accf[r][s] += (&af[r].x)[k] * (&bf[s].x)[k];
                }
            }
            // per-tile fp64 promotion (<=16 fp32 products per partial)
#pragma unroll
            for (int r = 0; r < 4; ++r)
#pragma unroll
                for (int c = 0; c < 4; ++c) {
                    acc[r][c] += (double)accf[r][c];
                    accf[r][c] = 0.0f;
                }
        }
    }

    // 4-lane t-split reduce (registers only), then sS overlay of sX
#pragma unroll
    for (int r = 0; r < 4; ++r)
#pragma unroll
        for (int c = 0; c < 4; ++c) {
            double v = acc[r][c];
            v += __shfl_xor(v, 1, 4);
            v += __shfl_xor(v, 2, 4);
            acc[r][c] = v;
        }
    __syncthreads();                 // all sX reads complete before overlay
    if (actA && myks == 0) {
#pragma unroll
        for (int r = 0; r < 4; ++r)
#pragma unroll
            for (int c = 0; c < 4; ++c)
                sS[(a0 + r) * SLD + (b0 + c)] = acc[r][c];
    }
    __syncthreads();

    // ---------------- Phase B: cov -> A -> Jacobi -> log-map ----------------
    if (tid < CC) sMean[tid] = sS[tid * SLD + 62] / (double)TT;
    __syncthreads();

    // packed cov_x = (S - T m m^T)/(T-1)
    for (int pi = tid; pi < VECN; pi += 576) {
        int i, j; decodePi(pi, i, j);
        sC[pi] = (sS[i * SLD + j] - (double)TT * sMean[i] * sMean[j]) / 1999.0;
    }
    __syncthreads();

    // sS dead -> zero fp32 sGf (overlay)
    for (int e = tid; e < CC * LDGF; e += 576) sGf[e] = 0.0f;
    __syncthreads();

    // A = W C W^T + eps I, chunks of 9 output columns; store fp32
    const int jj = tid >> 6, kk = tid & 63;
    for (int j0 = 0; j0 < CC; j0 += 9) {
        const int j = j0 + jj;
        if (kk < CC && j < CC) {
            const float* wr = cw + j * CC;
            double a = 0.0; int idx = kk;
            for (int l = 0; l < kk; ++l) { a += sC[idx] * (double)wr[l]; idx += 61 - l; }
            for (int l = kk; l < CC; ++l) { a += sC[idx] * (double)wr[l]; idx += 1; }
            sU[jj * 64 + kk] = a;    // u_j[k] = (C w_j)[k]
        }
        __syncthreads();
        const int i = kk;
        if (i < CC && j < CC && i <= j) {
            const float* wi = cw + i * CC;
            double a = (i == j) ? 1e-3 : 0.0;
            for (int l = 0; l < CC; ++l) a += (double)wi[l] * sU[jj * 64 + l];
            sGf[j * LDGF + i] = (float)a;
            sGf[i * LDGF + j] = (float)a;
        }
        __syncthreads();
    }

    // initial column norms n_k = ||g_k||^2 (fp64 accumulate over fp32 G)
    if (tid < CC) {
        const float* col = &sGf[tid * LDGF];
        double n = 0.0;
        for (int i2 = 0; i2 < CC; ++i2) n += (double)col[i2] * (double)col[i2];
        sNorm[tid] = n;
    }
    __syncthreads();

    // one-sided Jacobi: group g (16 lanes) handles pair g each round;
    // lane lt owns rows 4lt..4lt+3 (one float4 per column, b128).
    const int g = tid >> 4, lt = tid & 15;
    const bool actJ = (g < NG);
    const int r0 = 4 * lt;

    for (int sweep = 0; sweep < 20; ++sweep) {
        if (tid == 0) sFlag = 0;
        __syncthreads();
        for (int r = 0; r < 61; ++r) {
            if (actJ) {
                int pq = sPair[r * NG + g];
                int p = pq & 255, q = pq >> 8;
                float4* gp = reinterpret_cast<float4*>(&sGf[p * LDGF + r0]);
                float4* gq = reinterpret_cast<float4*>(&sGf[q * LDGF + r0]);
                float4 P = *gp, Q = *gq;
                float df = P.x * Q.x + P.y * Q.y + P.z * Q.z + P.w * Q.w;
                // 16-lane butterfly entirely on VALU: xor1/xor2 quad_perm;
                // row_half_mirror == xor4 and row_mirror == xor8 once values
                // are quad-/half-uniform. Bitwise-identical d on all lanes.
                { int t2 = __builtin_amdgcn_mov_dpp(__float_as_int(df), 0xB1, 0xF, 0xF, true);
                  df += __int_as_float(t2); }   // lane ^= 1
                { int t2 = __builtin_amdgcn_mov_dpp(__float_as_int(df), 0x4E, 0xF, 0xF, true);
                  df += __int_as_float(t2); }   // lane ^= 2
                { int t2 = __builtin_amdgcn_mov_dpp(__float_as_int(df), 0x141, 0xF, 0xF, true);
                  df += __int_as_float(t2); }   // row_half_mirror -> xor 4
                { int t2 = __builtin_amdgcn_mov_dpp(__float_as_int(df), 0x140, 0xF, 0xF, true);
                  df += __int_as_float(t2); }   // row_mirror -> xor 8
                double d = (double)df;
                double np = sNorm[p], nq = sNorm[q];
                if (d * d > np * nq * 1e-12) {
                    float thf = (float)(nq - np) / (2.0f * df);
                    float af2 = fabsf(thf);
                    float tf = 1.0f / (af2 + sqrtf(af2 * af2 + 1.0f));
                    if (thf < 0.0f) tf = -tf;
                    float cf = rsqrtf(tf * tf + 1.0f);
                    float sn = tf * cf;
                    *gp = make_float4(cf * P.x - sn * Q.x, cf * P.y - sn * Q.y,
                                      cf * P.z - sn * Q.z, cf * P.w - sn * Q.w);
                    *gq = make_float4(sn * P.x + cf * Q.x, sn * P.y + cf * Q.y,
                                      sn * P.z + cf * Q.z, sn * P.w + cf * Q.w);
                    if (lt == 0) {
                        double td = (double)tf * d;
                        sNorm[p] = np - td; sNorm[q] = nq + td;
                        sFlag = 1;
                    }
                }
            }
            __syncthreads();
        }
        int flag = sFlag;
        __syncthreads();
        if (!flag) break;
    }

    // lam_k^2 = ||g_k||^2 (fp64 from fp32 G); d_k = log(max(lam,1e-6))/lam^2
    if (tid < CC) {
        const float* col = &sGf[tid * LDGF];
        double n = 0.0;
        for (int i5 = 0; i5 < CC; ++i5) n += (double)col[i5] * (double)col[i5];
        double lamv = sqrt(n);
        sD[tid] = log(fmax(lamv, 1e-6)) / n;
    }
    __syncthreads();

    // triu vectorization into LDS (sVec overlays dead sC)
    for (int pi = tid; pi < VECN; pi += 576) {
        int i, j; decodePi(pi, i, j);
        double a = 0.0;
        for (int k2 = 0; k2 < CC; ++k2)
            a += sD[k2] * (double)sGf[k2 * LDGF + i] * (double)sGf[k2 * LDGF + j];
        sVec[pi] = (float)a;
    }
    __syncthreads();

    // ---------------- Phase C: MLP head ----------------
    if (wid < 8) {
        for (int hh = 0; hh < 8; ++hh) {
            const int h = wid * 8 + hh;
            const float* w = pw + (size_t)h * VECN;
            float a = 0.0f;
            for (int k = lane; k < VECN; k += 64) a += sVec[k] * w[k];
            a += __shfl_xor(a, 32); a += __shfl_xor(a, 16); a += __shfl_xor(a, 8);
            a += __shfl_xor(a, 4);  a += __shfl_xor(a, 2);  a += __shfl_xor(a, 1);
            if (lane == 0) sF[h] = fmaxf(a + pbias[h], 0.0f);
        }
    }
    __syncthreads();
    if (tid < NCLS) {
        float o = hb[tid];
        for (int hh = 0; hh < HID; ++hh) o += sF[hh] * hw[tid * HID + hh];
        out[b * NCLS + tid] = o;
    }
}

// ---------------------------------------------------------------------------
extern "C" void kernel_launch(void* const* d_in, const int* in_sizes, int n_in,
                              void* d_out, int out_size, void* d_ws, size_t ws_size,
                              hipStream_t stream)
{
    const float* x  = (const float*)d_in[0];
    const float* cw = (const float*)d_in[1];
    // d_in[2] = conv bias: cancels in covariance, unused
    const float* pw = (const float*)d_in[3];
    const float* pb = (const float*)d_in[4];
    const float* hw = (const float*)d_in[5];
    const float* hb = (const float*)d_in[6];
    float* out = (float*)d_out;

    // single fused dispatch; workspace unused
    fused<<<BB, 576, 0, stream>>>(x, cw, pw, pb, hw, hb, out);
}